// Round 9
// baseline (231.140 us; speedup 1.0000x reference)
//
#include <hip/hip_runtime.h>

// Flash-attention fwd, B=2,S=2048,H=16,D=128, logits = QK^T / D.
// Round 16: DELETE the cvt_bf16 pre-pass (was ~25us + a launch of the
// ~122us non-attn time; attn itself is at its structural ceiling ~87us
// after setprio/BK/pipeline levers all came back <=0). attn now reads
// fp32 Q/K/V directly and converts during staging with hardware
// v_cvt_pk_bf16_f32 (RNE -- same rounding as the old cvt pass, so staged
// bf16 bits and absmax are unchanged). V's pack-pair step becomes free:
// cpk(row0,row1) IS the packed-pair layout. K/V global fetch doubles
// (fp32, L3-resident); latency hidden by the full-iteration prefetch
// window. Everything else byte-identical to R13 (best: 86.9us attn):
// BQ=256/BK=64, 512thr, 8 waves x 32q, permlane P path, consistent O/L
// bfr rounding, LDS 71,680B, 2 blocks... 1 block/CU a 8 waves (2/SIMD).

#define SEQ   2048
#define NHEAD 16
#define DH    128
#define NB    2
#define BQ    256
#define BK    64
#define NTHR  512
#define KSTR  136   // ushorts; 272B row; conflict-free for 32-lane frag reads
#define VSTR  72    // ushorts; 144B row
#define NKV   (SEQ / BK)
#define KTILE (BK * KSTR)   // 8704 ushorts
#define VTILE (DH * VSTR)   // 9216 ushorts

typedef __attribute__((ext_vector_type(8)))  short bf16x8;
typedef __attribute__((ext_vector_type(16))) float f32x16;
typedef __attribute__((ext_vector_type(4)))  unsigned int u32x4;

// round-half-up to bf16; returns the bf16 value's fp32 bit pattern
__device__ __forceinline__ unsigned int bfr(float x) {
    unsigned int u = __builtin_bit_cast(unsigned int, x);
    return (u + 0x8000u) & 0xffff0000u;
}

// hardware RNE pack: dword = bf16(lo) | bf16(hi)<<16
__device__ __forceinline__ unsigned int cpk(float lo, float hi) {
    unsigned int d;
    asm("v_cvt_pk_bf16_f32 %0, %1, %2" : "=v"(d) : "v"(lo), "v"(hi));
    return d;
}

// exchange: a.hi32lanes <-> b.lo32lanes  (v_permlane32_swap_b32)
__device__ __forceinline__ void pl32(unsigned int& a, unsigned int& b) {
    asm("v_permlane32_swap_b32 %0, %1" : "+v"(a), "+v"(b));
}

// ---- attention (single pass; converts fp32->bf16 during staging)
__global__ __launch_bounds__(NTHR, 2) void attn_fwd(
    const float* __restrict__ Qb,
    const float* __restrict__ Kb,
    const float* __restrict__ Vb,
    float* __restrict__ O)
{
    __shared__ unsigned short Kl[2][KTILE];   // 2 x 17,408 B
    __shared__ unsigned short Vl[2][VTILE];   // 2 x 18,432 B  [d][k]

    const int tid  = threadIdx.x;
    const int wave = tid >> 6;    // 0..7
    const int lane = tid & 63;
    const int hx   = lane >> 5;   // 0/1
    const int l32  = lane & 31;

    const int b  = blockIdx.y >> 4;
    const int h  = blockIdx.y & 15;
    const int q0 = blockIdx.x * BQ;

    const size_t rs = (size_t)NHEAD * DH;   // 2048 elems between seq rows
    const float* qb = Qb + (size_t)b * SEQ * rs + (size_t)h * DH;
    const float* kb = Kb + (size_t)b * SEQ * rs + (size_t)h * DH;
    const float* vb = Vb + (size_t)b * SEQ * rs + (size_t)h * DH;

    // ---- Q as B-operand frags: B[k=d][n=q], n=l32, k=(lane>>5)*8+j (+c*16)
    // fp32 load + RNE cvt_pk (same bits as the old cvt pass produced).
    bf16x8 qf[8];
    {
        const float* qp = qb + (size_t)(q0 + wave * 32 + l32) * rs + hx * 8;
        #pragma unroll
        for (int c = 0; c < 8; ++c) {
            const float4 a  = *(const float4*)(qp + c * 16);
            const float4 b2 = *(const float4*)(qp + c * 16 + 4);
            u32x4 t;
            t.x = cpk(a.x,  a.y);  t.y = cpk(a.z,  a.w);
            t.z = cpk(b2.x, b2.y); t.w = cpk(b2.z, b2.w);
            qf[c] = __builtin_bit_cast(bf16x8, t);
        }
    }

    // ---- staging maps (512 threads; same index math as R13)
    // K: 1024 16B-chunks (64 keys x 16 chunks): 2 per thread, coalesced.
    int kgo[2], kls[2];
    #pragma unroll
    for (int p = 0; p < 2; ++p) {
        const int cidx = p * NTHR + tid;
        const int key  = cidx >> 4;
        const int cc   = cidx & 15;
        kgo[p] = key * (int)rs + cc * 8;   // float elements
        kls[p] = key * KSTR + cc * 8;      // ushort elements
    }
    // V: key-pair kp (0..31) x d-chunk dcv (0..15): 1 (pair, chunk) per thread.
    const int kp  = tid & 31;
    const int dcv = tid >> 5;   // 0..15

    f32x16 o4[4];
    #pragma unroll
    for (int t = 0; t < 4; ++t)
        #pragma unroll
        for (int r = 0; r < 16; ++r) o4[t][r] = 0.f;
    float lsum = 0.f;
    const float c1 = 1.44269504088896340736f / 128.0f;  // log2(e)/D

    // staged fp32 in flight (converted at LDS-write time)
    float4 krA[2], krB[2];            // K: 2 chunks x 8 floats
    float4 vr0a, vr0b, vr1a, vr1b;    // V: rows 2kp / 2kp+1, 8 floats each

    // prologue: stage tile 0 into buffer 0
    {
        #pragma unroll
        for (int p = 0; p < 2; ++p) {
            krA[p] = *(const float4*)(kb + kgo[p]);
            krB[p] = *(const float4*)(kb + kgo[p] + 4);
        }
        {
            const float* src = vb + (size_t)(2 * kp) * rs + dcv * 8;
            vr0a = *(const float4*)src;        vr0b = *(const float4*)(src + 4);
            vr1a = *(const float4*)(src + rs); vr1b = *(const float4*)(src + rs + 4);
        }
        #pragma unroll
        for (int p = 0; p < 2; ++p) {
            u32x4 t;
            t.x = cpk(krA[p].x, krA[p].y); t.y = cpk(krA[p].z, krA[p].w);
            t.z = cpk(krB[p].x, krB[p].y); t.w = cpk(krB[p].z, krB[p].w);
            *(u32x4*)&Kl[0][kls[p]] = t;
        }
        unsigned int* vw = (unsigned int*)&Vl[0][0];
        vw[(dcv * 8 + 0) * (VSTR / 2) + kp] = cpk(vr0a.x, vr1a.x);
        vw[(dcv * 8 + 1) * (VSTR / 2) + kp] = cpk(vr0a.y, vr1a.y);
        vw[(dcv * 8 + 2) * (VSTR / 2) + kp] = cpk(vr0a.z, vr1a.z);
        vw[(dcv * 8 + 3) * (VSTR / 2) + kp] = cpk(vr0a.w, vr1a.w);
        vw[(dcv * 8 + 4) * (VSTR / 2) + kp] = cpk(vr0b.x, vr1b.x);
        vw[(dcv * 8 + 5) * (VSTR / 2) + kp] = cpk(vr0b.y, vr1b.y);
        vw[(dcv * 8 + 6) * (VSTR / 2) + kp] = cpk(vr0b.z, vr1b.z);
        vw[(dcv * 8 + 7) * (VSTR / 2) + kp] = cpk(vr0b.w, vr1b.w);
    }
    __syncthreads();

    for (int kv = 0; kv < NKV; ++kv) {
        const int cur = kv & 1;
        const int k0n = ((kv + 1) & (NKV - 1)) * BK;

        // ---- issue next tile's global loads (consumed after compute)
        #pragma unroll
        for (int p = 0; p < 2; ++p) {
            krA[p] = *(const float4*)(kb + (size_t)k0n * rs + kgo[p]);
            krB[p] = *(const float4*)(kb + (size_t)k0n * rs + kgo[p] + 4);
        }
        {
            const float* src = vb + (size_t)(k0n + 2 * kp) * rs + dcv * 8;
            vr0a = *(const float4*)src;        vr0b = *(const float4*)(src + 4);
            vr1a = *(const float4*)(src + rs); vr1b = *(const float4*)(src + rs + 4);
        }

        const unsigned short* Kc = &Kl[cur][0];
        const unsigned short* Vc = &Vl[cur][0];

        #pragma unroll
        for (int kt = 0; kt < 2; ++kt) {
            // ---- S^T(32 keys x 32 q) = K * Q^T
            f32x16 s;
            #pragma unroll
            for (int r = 0; r < 16; ++r) s[r] = 0.f;
            #pragma unroll
            for (int c = 0; c < 8; ++c) {
                bf16x8 kf = *(const bf16x8*)&Kc[(kt * 32 + l32) * KSTR + c * 16 + hx * 8];
                s = __builtin_amdgcn_mfma_f32_32x32x16_bf16(kf, qf[c], s, 0, 0, 0);
            }

            // ---- exp2(s*c1), round to bf16 ONCE; lsum accumulates the
            // ROUNDED values (O/L consistency). lane holds
            // P[q=l32][key=(r&3)+8*(r>>2)+4*hx]; w[g][p]=keys(8g+4hx+2p,+1).
            unsigned int w[4][2];
            #pragma unroll
            for (int g = 0; g < 4; ++g) {
                const unsigned int u0 = bfr(__builtin_amdgcn_exp2f(s[g * 4 + 0] * c1));
                const unsigned int u1 = bfr(__builtin_amdgcn_exp2f(s[g * 4 + 1] * c1));
                const unsigned int u2 = bfr(__builtin_amdgcn_exp2f(s[g * 4 + 2] * c1));
                const unsigned int u3 = bfr(__builtin_amdgcn_exp2f(s[g * 4 + 3] * c1));
                lsum += (__builtin_bit_cast(float, u0) + __builtin_bit_cast(float, u1))
                      + (__builtin_bit_cast(float, u2) + __builtin_bit_cast(float, u3));
                w[g][0] = u1 | (u0 >> 16);
                w[g][1] = u3 | (u2 >> 16);
            }

            // ---- lane l <-> l+32 half-exchange -> PV A-frags in registers
            #pragma unroll
            for (int ks = 0; ks < 2; ++ks) {
                pl32(w[2 * ks][0], w[2 * ks + 1][0]);
                pl32(w[2 * ks][1], w[2 * ks + 1][1]);
            }
            bf16x8 pf[2];
            #pragma unroll
            for (int ks = 0; ks < 2; ++ks) {
                u32x4 t;
                t.x = w[2 * ks][0];
                t.y = w[2 * ks][1];
                t.z = w[2 * ks + 1][0];
                t.w = w[2 * ks + 1][1];
                pf[ks] = __builtin_bit_cast(bf16x8, t);
            }

            // ---- O += P V for this key-tile (wave-private, no barrier)
            #pragma unroll
            for (int ks = 0; ks < 2; ++ks)
                #pragma unroll
                for (int dt = 0; dt < 4; ++dt) {
                    bf16x8 vf = *(const bf16x8*)&Vc[(dt * 32 + l32) * VSTR
                                                    + kt * 32 + ks * 16 + hx * 8];
                    o4[dt] = __builtin_amdgcn_mfma_f32_32x32x16_bf16(pf[ks], vf, o4[dt], 0, 0, 0);
                }
        }

        // ---- convert + write staged next tile into the other buffer
        const int nxt = cur ^ 1;
        #pragma unroll
        for (int p = 0; p < 2; ++p) {
            u32x4 t;
            t.x = cpk(krA[p].x, krA[p].y); t.y = cpk(krA[p].z, krA[p].w);
            t.z = cpk(krB[p].x, krB[p].y); t.w = cpk(krB[p].z, krB[p].w);
            *(u32x4*)&Kl[nxt][kls[p]] = t;
        }
        {
            unsigned int* vw = (unsigned int*)&Vl[nxt][0];
            vw[(dcv * 8 + 0) * (VSTR / 2) + kp] = cpk(vr0a.x, vr1a.x);
            vw[(dcv * 8 + 1) * (VSTR / 2) + kp] = cpk(vr0a.y, vr1a.y);
            vw[(dcv * 8 + 2) * (VSTR / 2) + kp] = cpk(vr0a.z, vr1a.z);
            vw[(dcv * 8 + 3) * (VSTR / 2) + kp] = cpk(vr0a.w, vr1a.w);
            vw[(dcv * 8 + 4) * (VSTR / 2) + kp] = cpk(vr0b.x, vr1b.x);
            vw[(dcv * 8 + 5) * (VSTR / 2) + kp] = cpk(vr0b.y, vr1b.y);
            vw[(dcv * 8 + 6) * (VSTR / 2) + kp] = cpk(vr0b.z, vr1b.z);
            vw[(dcv * 8 + 7) * (VSTR / 2) + kp] = cpk(vr0b.w, vr1b.w);
        }
        __syncthreads();
    }

    // ---- epilogue: L per q, then normalize + store (coalesced 128B runs)
    lsum += __shfl_xor(lsum, 32, 64);
    const float inv = 1.0f / lsum;     // valid for q = l32 (both halves)
    float iv[16];
    #pragma unroll
    for (int r = 0; r < 16; ++r)
        iv[r] = __shfl(inv, (r & 3) + 8 * (r >> 2) + 4 * hx, 64);

    #pragma unroll
    for (int dt = 0; dt < 4; ++dt) {
        #pragma unroll
        for (int r = 0; r < 16; ++r) {
            const int ql = (r & 3) + 8 * (r >> 2) + 4 * hx;
            const int qg = q0 + wave * 32 + ql;
            O[(size_t)(b * SEQ + qg) * rs + (size_t)h * DH + dt * 32 + l32] = o4[dt][r] * iv[r];
        }
    }
}

extern "C" void kernel_launch(void* const* d_in, const int* in_sizes, int n_in,
                              void* d_out, int out_size, void* d_ws, size_t ws_size,
                              hipStream_t stream) {
    const float* q = (const float*)d_in[0];
    const float* k = (const float*)d_in[1];
    const float* v = (const float*)d_in[2];
    float* o = (float*)d_out;
    (void)d_ws; (void)ws_size;

    attn_fwd<<<dim3(SEQ / BQ, NB * NHEAD), dim3(NTHR), 0, stream>>>(q, k, v, o);
}

// Round 10
// 199.761 us; speedup vs baseline: 1.1571x; 1.1571x over previous
//
#include <hip/hip_runtime.h>

// Flash-attention fwd, B=2,S=2048,H=16,D=128, logits = QK^T / D.
// Round 17: revert R16's fp32 single-pass (attn 86.9->143: fp32 staging
// doubled VMEM ops + regs, latency no longer hidden). Back to R13 attn
// (best: 86.9us) with two safe cuts:
//  (1) cvt converts K,V only (100MB traffic ~17us, was 150MB ~25us); attn
//      converts Q inline at frag load via v_cvt_pk_bf16_f32 (RNE, same
//      bits as cvt produced -- R16-verified path, runs once per block).
//  (2) T1 XCD-swizzle: remap grid so each XCD owns 4 complete heads (all
//      8 q-blocks of a head on ONE XCD -> K/V fetched once per XCD, L2-
//      shared, instead of 8 XCDs each fetching). Bijective relabel only.
//      Signature: FETCH_SIZE 143 -> ~60-90MB.
// attn body otherwise byte-identical to R13: BQ=256/BK=64, 512 thr,
// 8 waves x 32q, permlane P path, consistent O/L bfr rounding, LDS 71,680B.

#define SEQ   2048
#define NHEAD 16
#define DH    128
#define NB    2
#define BQ    256
#define BK    64
#define NTHR  512
#define KSTR  136   // ushorts; 272B row; conflict-free for 32-lane frag reads
#define VSTR  72    // ushorts; 144B row
#define NKV   (SEQ / BK)
#define NELEM (NB * SEQ * NHEAD * DH)
#define KTILE (BK * KSTR)   // 8704 ushorts
#define VTILE (DH * VSTR)   // 9216 ushorts

typedef __attribute__((ext_vector_type(8)))  short bf16x8;
typedef __attribute__((ext_vector_type(16))) float f32x16;
typedef __attribute__((ext_vector_type(4)))  unsigned int u32x4;

__device__ __forceinline__ unsigned short f2bf(float x) {
    unsigned int u = __builtin_bit_cast(unsigned int, x);
    u += 0x7fffu + ((u >> 16) & 1u);
    return (unsigned short)(u >> 16);
}

// round-half-up to bf16; returns the bf16 value's fp32 bit pattern
__device__ __forceinline__ unsigned int bfr(float x) {
    unsigned int u = __builtin_bit_cast(unsigned int, x);
    return (u + 0x8000u) & 0xffff0000u;
}

// hardware RNE pack: dword = bf16(lo) | bf16(hi)<<16
__device__ __forceinline__ unsigned int cpk(float lo, float hi) {
    unsigned int d;
    asm("v_cvt_pk_bf16_f32 %0, %1, %2" : "=v"(d) : "v"(lo), "v"(hi));
    return d;
}

// exchange: a.hi32lanes <-> b.lo32lanes  (v_permlane32_swap_b32)
__device__ __forceinline__ void pl32(unsigned int& a, unsigned int& b) {
    asm("v_permlane32_swap_b32 %0, %1" : "+v"(a), "+v"(b));
}

// ---- pass 1: fp32 -> bf16 (RNE) for K and V only
__global__ __launch_bounds__(256) void cvt_bf16(
    const float* __restrict__ k, const float* __restrict__ v,
    unsigned short* __restrict__ dst)
{
    const int y = blockIdx.y;               // 0: K, 1: V
    const float* s = (y == 0) ? k : v;
    unsigned short* d = dst + (size_t)y * NELEM;
    const int i = blockIdx.x * 256 + threadIdx.x;
    const float4 x = ((const float4*)s)[i];
    ushort4 o;
    o.x = f2bf(x.x); o.y = f2bf(x.y); o.z = f2bf(x.z); o.w = f2bf(x.w);
    ((ushort4*)d)[i] = o;
}

// ---- pass 2: attention (Q converted inline, once per block)
__global__ __launch_bounds__(NTHR, 2) void attn_fwd(
    const float* __restrict__ Qb,
    const unsigned short* __restrict__ Kb,
    const unsigned short* __restrict__ Vb,
    float* __restrict__ O)
{
    __shared__ unsigned short Kl[2][KTILE];   // 2 x 17,408 B
    __shared__ unsigned short Vl[2][VTILE];   // 2 x 18,432 B  [d][k]

    const int tid  = threadIdx.x;
    const int wave = tid >> 6;    // 0..7
    const int lane = tid & 63;
    const int hx   = lane >> 5;   // 0/1
    const int l32  = lane & 31;

    // ---- T1 XCD-swizzle: linear bid -> (head-combo, q-tile) such that the
    // 8 q-blocks of each head share one XCD (bid%8 assumed XCD round-robin).
    // XCD k gets head-combos [4k, 4k+4), each with its 8 q-tiles.
    const int bid = blockIdx.x + (int)(blockIdx.y << 3);   // 0..255
    const int xk  = bid & 7;
    const int j   = bid >> 3;                              // 0..31
    const int hc  = (xk << 2) + (j >> 3);                  // 0..31
    const int b   = hc >> 4;
    const int h   = hc & 15;
    const int q0  = (j & 7) * BQ;

    const size_t rs = (size_t)NHEAD * DH;   // 2048 elems between seq rows
    const float*          qb = Qb + (size_t)b * SEQ * rs + (size_t)h * DH;
    const unsigned short* kb = Kb + (size_t)b * SEQ * rs + (size_t)h * DH;
    const unsigned short* vb = Vb + (size_t)b * SEQ * rs + (size_t)h * DH;

    // ---- Q as B-operand frags: B[k=d][n=q], n=l32, k=(lane>>5)*8+j (+c*16)
    // fp32 load + RNE cvt_pk: same bits the cvt pass would have staged.
    bf16x8 qf[8];
    {
        const float* qp = qb + (size_t)(q0 + wave * 32 + l32) * rs + hx * 8;
        #pragma unroll
        for (int c = 0; c < 8; ++c) {
            const float4 a  = *(const float4*)(qp + c * 16);
            const float4 b2 = *(const float4*)(qp + c * 16 + 4);
            u32x4 t;
            t.x = cpk(a.x,  a.y);  t.y = cpk(a.z,  a.w);
            t.z = cpk(b2.x, b2.y); t.w = cpk(b2.z, b2.w);
            qf[c] = __builtin_bit_cast(bf16x8, t);
        }
    }

    // ---- staging maps (512 threads; same as R13)
    // K: 1024 16B-chunks (64 keys x 16 chunks): 2 per thread, coalesced.
    int kgo[2], kls[2];
    #pragma unroll
    for (int p = 0; p < 2; ++p) {
        const int cidx = p * NTHR + tid;
        const int key  = cidx >> 4;
        const int cc   = cidx & 15;
        kgo[p] = key * (int)rs + cc * 8;
        kls[p] = key * KSTR + cc * 8;
    }
    // V: key-pair kp (0..31) x d-chunk dcv (0..15): 1 (pair, chunk) per thread.
    const int kp  = tid & 31;
    const int dcv = tid >> 5;   // 0..15

    f32x16 o4[4];
    #pragma unroll
    for (int t = 0; t < 4; ++t)
        #pragma unroll
        for (int r = 0; r < 16; ++r) o4[t][r] = 0.f;
    float lsum = 0.f;
    const float c1 = 1.44269504088896340736f / 128.0f;  // log2(e)/D

    bf16x8 kr[2], vr[2];

    // prologue: stage tile 0 into buffer 0
    {
        #pragma unroll
        for (int p = 0; p < 2; ++p) kr[p] = *(const bf16x8*)(kb + kgo[p]);
        {
            const unsigned short* src = vb + (size_t)(2 * kp) * rs + dcv * 8;
            vr[0] = *(const bf16x8*)src;
            vr[1] = *(const bf16x8*)(src + rs);
        }
        #pragma unroll
        for (int p = 0; p < 2; ++p) *(bf16x8*)&Kl[0][kls[p]] = kr[p];
        unsigned int* vw = (unsigned int*)&Vl[0][0];
        #pragma unroll
        for (int j2 = 0; j2 < 8; ++j2) {
            const unsigned int pr = ((unsigned int)(unsigned short)vr[0][j2])
                                  | (((unsigned int)(unsigned short)vr[1][j2]) << 16);
            vw[(dcv * 8 + j2) * (VSTR / 2) + kp] = pr;
        }
    }
    __syncthreads();

    for (int kv = 0; kv < NKV; ++kv) {
        const int cur = kv & 1;
        const int k0n = ((kv + 1) & (NKV - 1)) * BK;

        // ---- issue next tile's global loads (consumed after compute)
        #pragma unroll
        for (int p = 0; p < 2; ++p) kr[p] = *(const bf16x8*)(kb + (size_t)k0n * rs + kgo[p]);
        {
            const unsigned short* src = vb + (size_t)(k0n + 2 * kp) * rs + dcv * 8;
            vr[0] = *(const bf16x8*)src;
            vr[1] = *(const bf16x8*)(src + rs);
        }

        const unsigned short* Kc = &Kl[cur][0];
        const unsigned short* Vc = &Vl[cur][0];

        #pragma unroll
        for (int kt = 0; kt < 2; ++kt) {
            // ---- S^T(32 keys x 32 q) = K * Q^T
            f32x16 s;
            #pragma unroll
            for (int r = 0; r < 16; ++r) s[r] = 0.f;
            #pragma unroll
            for (int c = 0; c < 8; ++c) {
                bf16x8 kf = *(const bf16x8*)&Kc[(kt * 32 + l32) * KSTR + c * 16 + hx * 8];
                s = __builtin_amdgcn_mfma_f32_32x32x16_bf16(kf, qf[c], s, 0, 0, 0);
            }

            // ---- exp2(s*c1), round to bf16 ONCE; lsum accumulates the
            // ROUNDED values (O/L consistency). lane holds
            // P[q=l32][key=(r&3)+8*(r>>2)+4*hx]; w[g][p]=keys(8g+4hx+2p,+1).
            unsigned int w[4][2];
            #pragma unroll
            for (int g = 0; g < 4; ++g) {
                const unsigned int u0 = bfr(__builtin_amdgcn_exp2f(s[g * 4 + 0] * c1));
                const unsigned int u1 = bfr(__builtin_amdgcn_exp2f(s[g * 4 + 1] * c1));
                const unsigned int u2 = bfr(__builtin_amdgcn_exp2f(s[g * 4 + 2] * c1));
                const unsigned int u3 = bfr(__builtin_amdgcn_exp2f(s[g * 4 + 3] * c1));
                lsum += (__builtin_bit_cast(float, u0) + __builtin_bit_cast(float, u1))
                      + (__builtin_bit_cast(float, u2) + __builtin_bit_cast(float, u3));
                w[g][0] = u1 | (u0 >> 16);
                w[g][1] = u3 | (u2 >> 16);
            }

            // ---- lane l <-> l+32 half-exchange -> PV A-frags in registers
            #pragma unroll
            for (int ks = 0; ks < 2; ++ks) {
                pl32(w[2 * ks][0], w[2 * ks + 1][0]);
                pl32(w[2 * ks][1], w[2 * ks + 1][1]);
            }
            bf16x8 pf[2];
            #pragma unroll
            for (int ks = 0; ks < 2; ++ks) {
                u32x4 t;
                t.x = w[2 * ks][0];
                t.y = w[2 * ks][1];
                t.z = w[2 * ks + 1][0];
                t.w = w[2 * ks + 1][1];
                pf[ks] = __builtin_bit_cast(bf16x8, t);
            }

            // ---- O += P V for this key-tile (wave-private, no barrier)
            #pragma unroll
            for (int ks = 0; ks < 2; ++ks)
                #pragma unroll
                for (int dt = 0; dt < 4; ++dt) {
                    bf16x8 vf = *(const bf16x8*)&Vc[(dt * 32 + l32) * VSTR
                                                    + kt * 32 + ks * 16 + hx * 8];
                    o4[dt] = __builtin_amdgcn_mfma_f32_32x32x16_bf16(pf[ks], vf, o4[dt], 0, 0, 0);
                }
        }

        // ---- write staged next tile into the other buffer
        const int nxt = cur ^ 1;
        #pragma unroll
        for (int p = 0; p < 2; ++p) *(bf16x8*)&Kl[nxt][kls[p]] = kr[p];
        {
            unsigned int* vw = (unsigned int*)&Vl[nxt][0];
            #pragma unroll
            for (int j2 = 0; j2 < 8; ++j2) {
                const unsigned int pr = ((unsigned int)(unsigned short)vr[0][j2])
                                      | (((unsigned int)(unsigned short)vr[1][j2]) << 16);
                vw[(dcv * 8 + j2) * (VSTR / 2) + kp] = pr;
            }
        }
        __syncthreads();
    }

    // ---- epilogue: L per q, then normalize + store (coalesced 128B runs)
    lsum += __shfl_xor(lsum, 32, 64);
    const float inv = 1.0f / lsum;     // valid for q = l32 (both halves)
    float iv[16];
    #pragma unroll
    for (int r = 0; r < 16; ++r)
        iv[r] = __shfl(inv, (r & 3) + 8 * (r >> 2) + 4 * hx, 64);

    #pragma unroll
    for (int dt = 0; dt < 4; ++dt) {
        #pragma unroll
        for (int r = 0; r < 16; ++r) {
            const int ql = (r & 3) + 8 * (r >> 2) + 4 * hx;
            const int qg = q0 + wave * 32 + ql;
            O[(size_t)(b * SEQ + qg) * rs + (size_t)h * DH + dt * 32 + l32] = o4[dt][r] * iv[r];
        }
    }
}

extern "C" void kernel_launch(void* const* d_in, const int* in_sizes, int n_in,
                              void* d_out, int out_size, void* d_ws, size_t ws_size,
                              hipStream_t stream) {
    const float* q = (const float*)d_in[0];
    const float* k = (const float*)d_in[1];
    const float* v = (const float*)d_in[2];
    float* o = (float*)d_out;
    unsigned short* wsb = (unsigned short*)d_ws;

    cvt_bf16<<<dim3(NELEM / 1024, 2), 256, 0, stream>>>(k, v, wsb);
    attn_fwd<<<dim3(SEQ / BQ, NB * NHEAD), dim3(NTHR), 0, stream>>>(
        q, wsb, wsb + NELEM, o);
}